// Round 5
// baseline (499.109 us; speedup 1.0000x reference)
//
#include <hip/hip_runtime.h>

#define N_NODES 16384
#define N_EDGES 262144
#define HID 512
#define NG 256
#define NL 4
#define NOUT 128

typedef __attribute__((ext_vector_type(8))) short bf16x8;
typedef __attribute__((ext_vector_type(4))) float f32x4;
typedef __attribute__((ext_vector_type(8))) unsigned short u16x8;

static __device__ __forceinline__ unsigned short f2bf(float f) {
    unsigned int u = __float_as_uint(f);
    unsigned int r = (u + 0x7fffu + ((u >> 16) & 1u)) >> 16;
    return (unsigned short)r;
}
static __device__ __forceinline__ float bf2f(unsigned short s) {
    return __uint_as_float(((unsigned int)s) << 16);
}

// async 16B global -> LDS (wave-uniform LDS base + lane*16, per-lane global src)
static __device__ __forceinline__ void gload_lds16(const unsigned short* g, unsigned short* l) {
    __builtin_amdgcn_global_load_lds(
        (const __attribute__((address_space(1))) unsigned int*)(g),
        (__attribute__((address_space(3))) unsigned int*)(l), 16, 0, 0);
}

// ---------------- Fused prep: atom | count | wt | combo | gstart ----------------
// block ranges: [0,8192) atom, [8192,9216) count, [9216,13312) wt,
//               [13312,17408) combo, [17408] gstart
__global__ __launch_bounds__(256) void k_prep(const int* __restrict__ hn, const float* __restrict__ aemb,
                                              float* __restrict__ h, unsigned short* __restrict__ h_bf,
                                              const int* __restrict__ dst, int* __restrict__ cnt,
                                              const float* __restrict__ W, unsigned short* __restrict__ Wt,
                                              const float* __restrict__ bemb, unsigned short* __restrict__ ctab,
                                              const int* __restrict__ gid, int* __restrict__ gs,
                                              float* __restrict__ rcnt) {
    const int bid = blockIdx.x;
    const int tid = threadIdx.x;
    if (bid < 8192) {  // ---- atom encoder: 2 nodes/block
        int n = bid * 2 + (tid >> 7);
        int c = (tid & 127) * 4;
        float4 acc = make_float4(0.f, 0.f, 0.f, 0.f);
        for (int f = 0; f < 9; ++f) {
            int v = hn[n * 9 + f];
            const float4 ev = *(const float4*)(aemb + (size_t)(f * 128 + v) * HID + c);
            acc.x += ev.x; acc.y += ev.y; acc.z += ev.z; acc.w += ev.w;
        }
        *(float4*)(h + (size_t)n * HID + c) = acc;
        ushort4 pk;
        pk.x = f2bf(acc.x); pk.y = f2bf(acc.y); pk.z = f2bf(acc.z); pk.w = f2bf(acc.w);
        *(ushort4*)(h_bf + (size_t)n * HID + c) = pk;
    } else if (bid < 9216) {  // ---- indegree count
        int e = (bid - 8192) * 256 + tid;
        atomicAdd(&cnt[dst[e]], 1);
    } else if (bid < 13312) {  // ---- W transpose + bf16
        int id = (bid - 9216) * 256 + tid;
        int l = id >> 18;
        int n = (id >> 9) & 511;
        int k = id & 511;
        Wt[id] = f2bf(W[((size_t)l << 18) + ((size_t)k << 9) + n]);
    } else if (bid < 17408) {  // ---- bond combo table
        int id = (bid - 13312) * 256 + tid;
        int c = id & 511;
        int combo = (id >> 9) & 511;
        int l = id >> 18;
        int i0 = combo >> 6, i1 = (combo >> 3) & 7, i2 = combo & 7;
        const float* bl = bemb + (size_t)l * 3 * 8 * HID;
        float v = bl[(size_t)i0 * HID + c] + bl[(size_t)(8 + i1) * HID + c] + bl[(size_t)(16 + i2) * HID + c];
        ctab[id] = f2bf(v);
    } else {  // ---- graph segment starts (gid sorted)
        int g = tid;
        int lo = 0, hi = N_NODES;
        while (lo < hi) { int mid = (lo + hi) >> 1; if (gid[mid] < g) lo = mid + 1; else hi = mid; }
        gs[g] = lo;
        if (g == 0) gs[NG] = N_NODES;
        __syncthreads();
        int e = (g == NG - 1) ? N_NODES : gs[g + 1];
        rcnt[g] = 1.0f / fmaxf((float)(e - lo), 1.0f);
    }
}

__global__ void k_scan(const int* __restrict__ cnt, int* __restrict__ rs) {
    __shared__ int spre[256];
    int t = threadIdx.x;
    int base = t * 64;
    int s = 0;
    for (int i = 0; i < 64; ++i) s += cnt[base + i];
    spre[t] = s;
    __syncthreads();
    if (t == 0) {
        int run = 0;
        for (int i = 0; i < 256; ++i) { int v = spre[i]; spre[i] = run; run += v; }
        rs[N_NODES] = run;
    }
    __syncthreads();
    int run = spre[t];
    for (int i = 0; i < 64; ++i) { rs[base + i] = run; run += cnt[base + i]; }
}

// fill CSR slots directly with packed edge records (src, bond-combo)
__global__ void k_fillep(const int* __restrict__ dst, const int* __restrict__ rs,
                         int* __restrict__ fc, const int* __restrict__ src,
                         const int* __restrict__ hedge, int2* __restrict__ ep) {
    int e = blockIdx.x * 256 + threadIdx.x;
    int d = dst[e];
    int pos = atomicAdd(&fc[d], 1);
    int s = src[e];
    int c = hedge[e * 3 + 0] * 64 + hedge[e * 3 + 1] * 8 + hedge[e * 3 + 2];
    ep[rs[d] + pos] = make_int2(s, c);
}

// ---------------- Neighbor aggregate + combine + bf16 ----------------
#define NEDGE1(PX, PY)                                                          \
    {                                                                           \
        u16x8 a0 = *(const u16x8*)(h_bf + (size_t)(PX)*HID + c);                \
        u16x8 b0 = *(const u16x8*)(ctab + (size_t)(PY)*HID + c);                \
        _Pragma("unroll") for (int q = 0; q < 8; ++q)                           \
            acc[q] += bf2f(a0[q]) + bf2f(b0[q]);                                \
    }

__global__ __launch_bounds__(256) void k_neigh(const unsigned short* __restrict__ h_bf,
                                               const int2* __restrict__ ep,
                                               const int* __restrict__ rs,
                                               const unsigned short* __restrict__ ctab,
                                               unsigned short* __restrict__ t) {
    int n = blockIdx.x * 4 + (threadIdx.x >> 6);
    int c = (threadIdx.x & 63) * 8;
    int s = rs[n], e = rs[n + 1];
    u16x8 hself = *(const u16x8*)(h_bf + (size_t)n * HID + c);
    float acc[8] = {0.f, 0.f, 0.f, 0.f, 0.f, 0.f, 0.f, 0.f};
    int j = s;
    if (j < e && (j & 1)) {  // peel to 16B-align ep for int4 loads
        int2 p = ep[j];
        NEDGE1(p.x, p.y)
        ++j;
    }
    for (; j + 4 <= e; j += 4) {
        int4 pa = *(const int4*)(ep + j);
        int4 pb = *(const int4*)(ep + j + 2);
        u16x8 a0 = *(const u16x8*)(h_bf + (size_t)pa.x * HID + c);
        u16x8 b0 = *(const u16x8*)(ctab + (size_t)pa.y * HID + c);
        u16x8 a1 = *(const u16x8*)(h_bf + (size_t)pa.z * HID + c);
        u16x8 b1 = *(const u16x8*)(ctab + (size_t)pa.w * HID + c);
        u16x8 a2 = *(const u16x8*)(h_bf + (size_t)pb.x * HID + c);
        u16x8 b2 = *(const u16x8*)(ctab + (size_t)pb.y * HID + c);
        u16x8 a3 = *(const u16x8*)(h_bf + (size_t)pb.z * HID + c);
        u16x8 b3 = *(const u16x8*)(ctab + (size_t)pb.w * HID + c);
        #pragma unroll
        for (int q = 0; q < 8; ++q)
            acc[q] += ((bf2f(a0[q]) + bf2f(b0[q])) + (bf2f(a1[q]) + bf2f(b1[q])))
                    + ((bf2f(a2[q]) + bf2f(b2[q])) + (bf2f(a3[q]) + bf2f(b3[q])));
    }
    for (; j < e; ++j) {
        int2 p = ep[j];
        NEDGE1(p.x, p.y)
    }
    float inv = 1.0f / fmaxf((float)(e - s), 1.0f);
    u16x8 pk;
    #pragma unroll
    for (int q = 0; q < 8; ++q)
        pk[q] = f2bf(bf2f(hself[q]) + acc[q] * inv);
    *(u16x8*)(t + (size_t)n * HID + c) = pk;
}

// ---------------- GEMM: r_bf[M,512] = bf16(A @ W + bias) ----------------
#define BM 128
#define BN 64
#define BK 64

__global__ __launch_bounds__(256) void k_gemm(const unsigned short* __restrict__ A,
                                              const unsigned short* __restrict__ Bt,
                                              const float* __restrict__ bias,
                                              unsigned short* __restrict__ C) {
    __shared__ unsigned short As[BM * BK];
    __shared__ unsigned short Bs[BN * BK];
    const int tid = threadIdx.x;
    const int m0 = blockIdx.x * BM;
    const int n0 = blockIdx.y * BN;
    const int w = tid >> 6, lane = tid & 63;
    const int wm = (w >> 1) * 64, wn = (w & 1) * 32;
    const int lr = lane & 15, lg = lane >> 4;

    const int srow = tid >> 3;
    const int scol = ((tid & 7) ^ (srow & 7)) * 8;

    f32x4 acc[4][2] = {};

    for (int k0 = 0; k0 < HID; k0 += BK) {
        __syncthreads();
        #pragma unroll
        for (int r = 0; r < 4; ++r)
            gload_lds16(A + (size_t)(m0 + r * 32 + srow) * HID + k0 + scol,
                        As + r * 2048 + w * 512);
        #pragma unroll
        for (int r = 0; r < 2; ++r)
            gload_lds16(Bt + (size_t)(n0 + r * 32 + srow) * HID + k0 + scol,
                        Bs + r * 2048 + w * 512);
        __syncthreads();

        #pragma unroll
        for (int kk = 0; kk < 2; ++kk) {
            bf16x8 af[4], bfr[2];
            #pragma unroll
            for (int i = 0; i < 4; ++i) {
                int row = wm + i * 16 + lr;
                af[i] = *(const bf16x8*)(As + row * BK + (((kk * 4 + lg) ^ (row & 7)) * 8));
            }
            #pragma unroll
            for (int j = 0; j < 2; ++j) {
                int row = wn + j * 16 + lr;
                bfr[j] = *(const bf16x8*)(Bs + row * BK + (((kk * 4 + lg) ^ (row & 7)) * 8));
            }
            #pragma unroll
            for (int i = 0; i < 4; ++i)
                #pragma unroll
                for (int j = 0; j < 2; ++j)
                    acc[i][j] = __builtin_amdgcn_mfma_f32_16x16x32_bf16(af[i], bfr[j], acc[i][j], 0, 0, 0);
        }
    }

    #pragma unroll
    for (int i = 0; i < 4; ++i) {
        const int grow = m0 + wm + i * 16 + lg * 4;
        #pragma unroll
        for (int j = 0; j < 2; ++j) {
            const int gcol = n0 + wn + j * 16 + lr;
            const float bv = bias[gcol];
            #pragma unroll
            for (int rr = 0; rr < 4; ++rr)
                C[(size_t)(grow + rr) * HID + gcol] = f2bf(acc[i][j][rr] + bv);
        }
    }
}

// ---------------- GraphNorm stats: per-segment partials (no atomics) ----------------
__global__ __launch_bounds__(256) void k_gstats(const unsigned short* __restrict__ r,
                                                const int* __restrict__ gs,
                                                float* __restrict__ psum, float* __restrict__ psq) {
    int g = blockIdx.x;
    int seg = blockIdx.y;
    int s = gs[g], e = gs[g + 1];
    int c = threadIdx.x * 2;
    float s0 = 0.f, s1 = 0.f, q0 = 0.f, q1 = 0.f;
    for (int n = s + seg; n < e; n += 8) {
        ushort2 v = *(const ushort2*)(r + (size_t)n * HID + c);
        float v0 = bf2f(v.x), v1 = bf2f(v.y);
        s0 += v0; s1 += v1; q0 += v0 * v0; q1 += v1 * v1;
    }
    size_t o = ((size_t)seg * NG + g) * HID + c;
    *(float2*)(psum + o) = make_float2(s0, s1);
    *(float2*)(psq + o) = make_float2(q0, q1);
}

// reduce 8 segment partials -> gsum/gsq
__global__ __launch_bounds__(256) void k_gred(const float* __restrict__ psum, const float* __restrict__ psq,
                                              float* __restrict__ gsum, float* __restrict__ gsq) {
    int idx = blockIdx.x * 256 + threadIdx.x;  // NG*HID
    float s = 0.f, q = 0.f;
    #pragma unroll
    for (int seg = 0; seg < 8; ++seg) {
        s += psum[(size_t)seg * NG * HID + idx];
        q += psq[(size_t)seg * NG * HID + idx];
    }
    gsum[idx] = s;
    gsq[idx] = q;
}

// ---------------- GraphNorm apply + ReLU + residual (layers 0..L-2) ----------------
__global__ __launch_bounds__(256) void k_gapply(const unsigned short* __restrict__ r, float* __restrict__ h,
                                                unsigned short* __restrict__ h_bf,
                                                const int* __restrict__ gid,
                                                const float* __restrict__ rcnt,
                                                const float* __restrict__ gsum, const float* __restrict__ gsq,
                                                const float* __restrict__ gw, const float* __restrict__ gb,
                                                const float* __restrict__ gms) {
    int n = blockIdx.x * 2 + (threadIdx.x >> 7);
    int c = (threadIdx.x & 127) * 4;
    int g = gid[n];
    float rc = rcnt[g];
    const float4 sm = *(const float4*)(gsum + (size_t)g * HID + c);
    const float4 sq = *(const float4*)(gsq + (size_t)g * HID + c);
    const float4 ms = *(const float4*)(gms + c);
    const float4 gwv = *(const float4*)(gw + c);
    const float4 gbv = *(const float4*)(gb + c);
    const ushort4 rv4 = *(const ushort4*)(r + (size_t)n * HID + c);
    const float4 hv = *(const float4*)(h + (size_t)n * HID + c);
    float rv[4] = {bf2f(rv4.x), bf2f(rv4.y), bf2f(rv4.z), bf2f(rv4.w)};
    float4 outv;
    float mean, am, var, wgt, v;
    #define CH(X, K)                                                \
        mean = sm.X * rc; am = ms.X * mean;                         \
        var = sq.X * rc - 2.f * am * mean + am * am;                \
        wgt = gwv.X * rsqrtf(var + 1e-6f);                          \
        v = (rv[K] - am) * wgt + gbv.X;                             \
        v = fmaxf(v, 0.f);                                         \
        outv.X = v + hv.X;
    CH(x, 0)
    CH(y, 1)
    CH(z, 2)
    CH(w, 3)
    #undef CH
    *(float4*)(h + (size_t)n * HID + c) = outv;
    ushort4 pk;
    pk.x = f2bf(outv.x); pk.y = f2bf(outv.y); pk.z = f2bf(outv.z); pk.w = f2bf(outv.w);
    *(ushort4*)(h_bf + (size_t)n * HID + c) = pk;
}

// ---------------- Last layer: GraphNorm apply + residual + fused pooling ----------------
__global__ __launch_bounds__(256) void k_gapply_pool(const unsigned short* __restrict__ r,
                                                     const float* __restrict__ h,
                                                     const int* __restrict__ gid,
                                                     const float* __restrict__ rcnt,
                                                     const float* __restrict__ gsum, const float* __restrict__ gsq,
                                                     const float* __restrict__ gw, const float* __restrict__ gb,
                                                     const float* __restrict__ gms,
                                                     float* __restrict__ pooled) {
    int n = blockIdx.x * 2 + (threadIdx.x >> 7);
    int c = (threadIdx.x & 127) * 4;
    int g = gid[n];
    float rc = rcnt[g];
    const float4 sm = *(const float4*)(gsum + (size_t)g * HID + c);
    const float4 sq = *(const float4*)(gsq + (size_t)g * HID + c);
    const float4 ms = *(const float4*)(gms + c);
    const float4 gwv = *(const float4*)(gw + c);
    const float4 gbv = *(const float4*)(gb + c);
    const ushort4 rv4 = *(const ushort4*)(r + (size_t)n * HID + c);
    const float4 hv = *(const float4*)(h + (size_t)n * HID + c);
    float rv[4] = {bf2f(rv4.x), bf2f(rv4.y), bf2f(rv4.z), bf2f(rv4.w)};
    float4 outv;
    float mean, am, var, wgt, v;
    #define CH(X, K)                                                \
        mean = sm.X * rc; am = ms.X * mean;                         \
        var = sq.X * rc - 2.f * am * mean + am * am;                \
        wgt = gwv.X * rsqrtf(var + 1e-6f);                          \
        v = (rv[K] - am) * wgt + gbv.X;                             \
        outv.X = v + hv.X;
    CH(x, 0)
    CH(y, 1)
    CH(z, 2)
    CH(w, 3)
    #undef CH
    atomicAdd(&pooled[(size_t)g * HID + c], outv.x);
    atomicAdd(&pooled[(size_t)g * HID + c + 1], outv.y);
    atomicAdd(&pooled[(size_t)g * HID + c + 2], outv.z);
    atomicAdd(&pooled[(size_t)g * HID + c + 3], outv.w);
}

// ---------------- Final projection ----------------
__global__ void k_proj(const float* __restrict__ pooled, const float* __restrict__ Wp,
                       const float* __restrict__ bp, float* __restrict__ out) {
    int g = blockIdx.x;
    int o = threadIdx.x;
    float acc = bp[o];
    const float* pr = pooled + (size_t)g * HID;
    #pragma unroll 8
    for (int k = 0; k < HID; ++k) acc += pr[k] * Wp[k * NOUT + o];
    out[g * NOUT + o] = acc;
}

extern "C" void kernel_launch(void* const* d_in, const int* in_sizes, int n_in,
                              void* d_out, int out_size, void* d_ws, size_t ws_size,
                              hipStream_t stream) {
    const int*   h_node = (const int*)d_in[0];
    const int*   h_edge = (const int*)d_in[1];
    const int*   src    = (const int*)d_in[2];
    const int*   dst    = (const int*)d_in[3];
    const int*   gid    = (const int*)d_in[4];
    const float* aemb   = (const float*)d_in[5];
    const float* bemb   = (const float*)d_in[6];
    const float* W      = (const float*)d_in[7];
    const float* bias   = (const float*)d_in[8];
    const float* gnw    = (const float*)d_in[9];
    const float* gnb    = (const float*)d_in[10];
    const float* gnms   = (const float*)d_in[11];
    const float* Wp     = (const float*)d_in[12];
    const float* bp     = (const float*)d_in[13];
    float* out = (float*)d_out;

    char* ws = (char*)d_ws;
    size_t off = 0;
    auto alloc = [&](size_t bytes) -> char* {
        char* p = ws + off;
        off += (bytes + 255) & ~(size_t)255;
        return p;
    };
    // zero-group first (one contiguous memset): cnt | fc | pooled
    int* cnt            = (int*)alloc((size_t)N_NODES * 4);
    int* fc             = (int*)alloc((size_t)N_NODES * 4);
    float* pooled       = (float*)alloc((size_t)NG * HID * 4);
    size_t zbytes = off;

    float* h            = (float*)alloc((size_t)N_NODES * HID * 4);
    unsigned short* rbf = (unsigned short*)alloc((size_t)N_NODES * HID * 2);
    unsigned short* t   = (unsigned short*)alloc((size_t)N_NODES * HID * 2);
    unsigned short* h_bf= (unsigned short*)alloc((size_t)N_NODES * HID * 2);
    unsigned short* Wt  = (unsigned short*)alloc((size_t)NL * HID * HID * 2);
    unsigned short* ctab= (unsigned short*)alloc((size_t)NL * 512 * HID * 2);
    int2* ep            = (int2*)alloc((size_t)N_EDGES * 8);
    int* rs             = (int*)alloc((size_t)(N_NODES + 1) * 4);
    int* gs             = (int*)alloc((size_t)(NG + 1) * 4);
    float* rcnt         = (float*)alloc((size_t)NG * 4);
    float* pstat        = (float*)alloc((size_t)2 * 8 * NG * HID * 4);
    float* gstat        = (float*)alloc((size_t)2 * NG * HID * 4);
    float* psum = pstat;
    float* psq  = pstat + (size_t)8 * NG * HID;
    float* gsum = gstat;
    float* gsq  = gstat + (size_t)NG * HID;

    hipMemsetAsync(cnt, 0, zbytes, stream);
    k_prep<<<17409, 256, 0, stream>>>(h_node, aemb, h, h_bf, dst, cnt, W, Wt, bemb, ctab,
                                      gid, gs, rcnt);
    k_scan<<<1, 256, 0, stream>>>(cnt, rs);
    k_fillep<<<N_EDGES / 256, 256, 0, stream>>>(dst, rs, fc, src, h_edge, ep);

    for (int i = 0; i < NL; ++i) {
        k_neigh<<<N_NODES / 4, 256, 0, stream>>>(h_bf, ep, rs,
                                                 ctab + (size_t)i * 512 * HID, t);
        dim3 gg(N_NODES / BM, HID / BN);
        k_gemm<<<gg, 256, 0, stream>>>(t, Wt + (size_t)i * HID * HID, bias + i * HID, rbf);
        k_gstats<<<dim3(NG, 8), 256, 0, stream>>>(rbf, gs, psum, psq);
        k_gred<<<NG * HID / 256, 256, 0, stream>>>(psum, psq, gsum, gsq);
        if (i < NL - 1) {
            k_gapply<<<N_NODES / 2, 256, 0, stream>>>(rbf, h, h_bf, gid, rcnt, gsum, gsq,
                                                      gnw + i * HID, gnb + i * HID, gnms + i * HID);
        } else {
            k_gapply_pool<<<N_NODES / 2, 256, 0, stream>>>(rbf, h, gid, rcnt, gsum, gsq,
                                                           gnw + i * HID, gnb + i * HID, gnms + i * HID,
                                                           pooled);
        }
    }
    k_proj<<<NG, NOUT, 0, stream>>>(pooled, Wp, bp, out);
}

// Round 6
// 376.527 us; speedup vs baseline: 1.3256x; 1.3256x over previous
//
#include <hip/hip_runtime.h>

#define N_NODES 16384
#define N_EDGES 262144
#define HID 512
#define NG 256
#define NL 4
#define NOUT 128

typedef __attribute__((ext_vector_type(8))) short bf16x8;
typedef __attribute__((ext_vector_type(4))) float f32x4;
typedef __attribute__((ext_vector_type(8))) unsigned short u16x8;

static __device__ __forceinline__ unsigned short f2bf(float f) {
    unsigned int u = __float_as_uint(f);
    unsigned int r = (u + 0x7fffu + ((u >> 16) & 1u)) >> 16;
    return (unsigned short)r;
}
static __device__ __forceinline__ float bf2f(unsigned short s) {
    return __uint_as_float(((unsigned int)s) << 16);
}

// async 16B global -> LDS (wave-uniform LDS base + lane*16, per-lane global src)
static __device__ __forceinline__ void gload_lds16(const unsigned short* g, unsigned short* l) {
    __builtin_amdgcn_global_load_lds(
        (const __attribute__((address_space(1))) unsigned int*)(g),
        (__attribute__((address_space(3))) unsigned int*)(l), 16, 0, 0);
}

// ---------------- Fused prep: atom | count | wt | combo | gstart ----------------
// block ranges: [0,8192) atom, [8192,9216) count, [9216,13312) wt,
//               [13312,17408) combo, [17408] gstart
__global__ __launch_bounds__(256) void k_prep(const int* __restrict__ hn, const float* __restrict__ aemb,
                                              unsigned short* __restrict__ h_bf,
                                              const int* __restrict__ dst, int* __restrict__ cnt,
                                              const float* __restrict__ W, unsigned short* __restrict__ Wt,
                                              const float* __restrict__ bemb, unsigned short* __restrict__ ctab,
                                              const int* __restrict__ gid, int* __restrict__ gs,
                                              float* __restrict__ rcnt) {
    const int bid = blockIdx.x;
    const int tid = threadIdx.x;
    if (bid < 8192) {  // ---- atom encoder: 2 nodes/block
        int n = bid * 2 + (tid >> 7);
        int c = (tid & 127) * 4;
        float4 acc = make_float4(0.f, 0.f, 0.f, 0.f);
        for (int f = 0; f < 9; ++f) {
            int v = hn[n * 9 + f];
            const float4 ev = *(const float4*)(aemb + (size_t)(f * 128 + v) * HID + c);
            acc.x += ev.x; acc.y += ev.y; acc.z += ev.z; acc.w += ev.w;
        }
        ushort4 pk;
        pk.x = f2bf(acc.x); pk.y = f2bf(acc.y); pk.z = f2bf(acc.z); pk.w = f2bf(acc.w);
        *(ushort4*)(h_bf + (size_t)n * HID + c) = pk;
    } else if (bid < 9216) {  // ---- indegree count
        int e = (bid - 8192) * 256 + tid;
        atomicAdd(&cnt[dst[e]], 1);
    } else if (bid < 13312) {  // ---- W transpose + bf16
        int id = (bid - 9216) * 256 + tid;
        int l = id >> 18;
        int n = (id >> 9) & 511;
        int k = id & 511;
        Wt[id] = f2bf(W[((size_t)l << 18) + ((size_t)k << 9) + n]);
    } else if (bid < 17408) {  // ---- bond combo table
        int id = (bid - 13312) * 256 + tid;
        int c = id & 511;
        int combo = (id >> 9) & 511;
        int l = id >> 18;
        int i0 = combo >> 6, i1 = (combo >> 3) & 7, i2 = combo & 7;
        const float* bl = bemb + (size_t)l * 3 * 8 * HID;
        float v = bl[(size_t)i0 * HID + c] + bl[(size_t)(8 + i1) * HID + c] + bl[(size_t)(16 + i2) * HID + c];
        ctab[id] = f2bf(v);
    } else {  // ---- graph segment starts (gid sorted)
        int g = tid;
        int lo = 0, hi = N_NODES;
        while (lo < hi) { int mid = (lo + hi) >> 1; if (gid[mid] < g) lo = mid + 1; else hi = mid; }
        gs[g] = lo;
        if (g == 0) gs[NG] = N_NODES;
        __syncthreads();
        int e = (g == NG - 1) ? N_NODES : gs[g + 1];
        rcnt[g] = 1.0f / fmaxf((float)(e - lo), 1.0f);
    }
}

__global__ void k_scan(const int* __restrict__ cnt, int* __restrict__ rs) {
    __shared__ int spre[256];
    int t = threadIdx.x;
    int base = t * 64;
    int s = 0;
    for (int i = 0; i < 64; ++i) s += cnt[base + i];
    spre[t] = s;
    __syncthreads();
    if (t == 0) {
        int run = 0;
        for (int i = 0; i < 256; ++i) { int v = spre[i]; spre[i] = run; run += v; }
        rs[N_NODES] = run;
    }
    __syncthreads();
    int run = spre[t];
    for (int i = 0; i < 64; ++i) { rs[base + i] = run; run += cnt[base + i]; }
}

// fill CSR slots directly with packed edge records (src, bond-combo)
__global__ void k_fillep(const int* __restrict__ dst, const int* __restrict__ rs,
                         int* __restrict__ fc, const int* __restrict__ src,
                         const int* __restrict__ hedge, int2* __restrict__ ep) {
    int e = blockIdx.x * 256 + threadIdx.x;
    int d = dst[e];
    int pos = atomicAdd(&fc[d], 1);
    int s = src[e];
    int c = hedge[e * 3 + 0] * 64 + hedge[e * 3 + 1] * 8 + hedge[e * 3 + 2];
    ep[rs[d] + pos] = make_int2(s, c);
}

// ---------------- Neighbor aggregate + combine + bf16 ----------------
#define NEDGE1(PX, PY)                                                          \
    {                                                                           \
        u16x8 a0 = *(const u16x8*)(h_bf + (size_t)(PX)*HID + c);                \
        u16x8 b0 = *(const u16x8*)(ctab + (size_t)(PY)*HID + c);                \
        _Pragma("unroll") for (int q = 0; q < 8; ++q)                           \
            acc[q] += bf2f(a0[q]) + bf2f(b0[q]);                                \
    }

__global__ __launch_bounds__(256) void k_neigh(const unsigned short* __restrict__ h_bf,
                                               const int2* __restrict__ ep,
                                               const int* __restrict__ rs,
                                               const unsigned short* __restrict__ ctab,
                                               unsigned short* __restrict__ t) {
    int n = blockIdx.x * 4 + (threadIdx.x >> 6);
    int c = (threadIdx.x & 63) * 8;
    int s = rs[n], e = rs[n + 1];
    u16x8 hself = *(const u16x8*)(h_bf + (size_t)n * HID + c);
    float acc[8] = {0.f, 0.f, 0.f, 0.f, 0.f, 0.f, 0.f, 0.f};
    int j = s;
    if (j < e && (j & 1)) {  // peel to 16B-align ep for int4 loads
        int2 p = ep[j];
        NEDGE1(p.x, p.y)
        ++j;
    }
    for (; j + 4 <= e; j += 4) {
        int4 pa = *(const int4*)(ep + j);
        int4 pb = *(const int4*)(ep + j + 2);
        u16x8 a0 = *(const u16x8*)(h_bf + (size_t)pa.x * HID + c);
        u16x8 b0 = *(const u16x8*)(ctab + (size_t)pa.y * HID + c);
        u16x8 a1 = *(const u16x8*)(h_bf + (size_t)pa.z * HID + c);
        u16x8 b1 = *(const u16x8*)(ctab + (size_t)pa.w * HID + c);
        u16x8 a2 = *(const u16x8*)(h_bf + (size_t)pb.x * HID + c);
        u16x8 b2 = *(const u16x8*)(ctab + (size_t)pb.y * HID + c);
        u16x8 a3 = *(const u16x8*)(h_bf + (size_t)pb.z * HID + c);
        u16x8 b3 = *(const u16x8*)(ctab + (size_t)pb.w * HID + c);
        #pragma unroll
        for (int q = 0; q < 8; ++q)
            acc[q] += ((bf2f(a0[q]) + bf2f(b0[q])) + (bf2f(a1[q]) + bf2f(b1[q])))
                    + ((bf2f(a2[q]) + bf2f(b2[q])) + (bf2f(a3[q]) + bf2f(b3[q])));
    }
    for (; j < e; ++j) {
        int2 p = ep[j];
        NEDGE1(p.x, p.y)
    }
    float inv = 1.0f / fmaxf((float)(e - s), 1.0f);
    u16x8 pk;
    #pragma unroll
    for (int q = 0; q < 8; ++q)
        pk[q] = f2bf(bf2f(hself[q]) + acc[q] * inv);
    *(u16x8*)(t + (size_t)n * HID + c) = pk;
}

// ---------------- GEMM: r_bf[M,512] = bf16(A @ W + bias) ----------------
#define BM 128
#define BN 64
#define BK 64

__global__ __launch_bounds__(256) void k_gemm(const unsigned short* __restrict__ A,
                                              const unsigned short* __restrict__ Bt,
                                              const float* __restrict__ bias,
                                              unsigned short* __restrict__ C) {
    __shared__ unsigned short As[BM * BK];
    __shared__ unsigned short Bs[BN * BK];
    const int tid = threadIdx.x;
    const int m0 = blockIdx.x * BM;
    const int n0 = blockIdx.y * BN;
    const int w = tid >> 6, lane = tid & 63;
    const int wm = (w >> 1) * 64, wn = (w & 1) * 32;
    const int lr = lane & 15, lg = lane >> 4;

    const int srow = tid >> 3;
    const int scol = ((tid & 7) ^ (srow & 7)) * 8;

    f32x4 acc[4][2] = {};

    for (int k0 = 0; k0 < HID; k0 += BK) {
        __syncthreads();
        #pragma unroll
        for (int r = 0; r < 4; ++r)
            gload_lds16(A + (size_t)(m0 + r * 32 + srow) * HID + k0 + scol,
                        As + r * 2048 + w * 512);
        #pragma unroll
        for (int r = 0; r < 2; ++r)
            gload_lds16(Bt + (size_t)(n0 + r * 32 + srow) * HID + k0 + scol,
                        Bs + r * 2048 + w * 512);
        __syncthreads();

        #pragma unroll
        for (int kk = 0; kk < 2; ++kk) {
            bf16x8 af[4], bfr[2];
            #pragma unroll
            for (int i = 0; i < 4; ++i) {
                int row = wm + i * 16 + lr;
                af[i] = *(const bf16x8*)(As + row * BK + (((kk * 4 + lg) ^ (row & 7)) * 8));
            }
            #pragma unroll
            for (int j = 0; j < 2; ++j) {
                int row = wn + j * 16 + lr;
                bfr[j] = *(const bf16x8*)(Bs + row * BK + (((kk * 4 + lg) ^ (row & 7)) * 8));
            }
            #pragma unroll
            for (int i = 0; i < 4; ++i)
                #pragma unroll
                for (int j = 0; j < 2; ++j)
                    acc[i][j] = __builtin_amdgcn_mfma_f32_16x16x32_bf16(af[i], bfr[j], acc[i][j], 0, 0, 0);
        }
    }

    #pragma unroll
    for (int i = 0; i < 4; ++i) {
        const int grow = m0 + wm + i * 16 + lg * 4;
        #pragma unroll
        for (int j = 0; j < 2; ++j) {
            const int gcol = n0 + wn + j * 16 + lr;
            const float bv = bias[gcol];
            #pragma unroll
            for (int rr = 0; rr < 4; ++rr)
                C[(size_t)(grow + rr) * HID + gcol] = f2bf(acc[i][j][rr] + bv);
        }
    }
}

// ---------------- GraphNorm stats: per-segment partials (no atomics) ----------------
__global__ __launch_bounds__(256) void k_gstats(const unsigned short* __restrict__ r,
                                                const int* __restrict__ gs,
                                                float* __restrict__ psum, float* __restrict__ psq) {
    int g = blockIdx.x;
    int seg = blockIdx.y;
    int s = gs[g], e = gs[g + 1];
    int c = threadIdx.x * 2;
    float s0 = 0.f, s1 = 0.f, q0 = 0.f, q1 = 0.f;
    for (int n = s + seg; n < e; n += 8) {
        ushort2 v = *(const ushort2*)(r + (size_t)n * HID + c);
        float v0 = bf2f(v.x), v1 = bf2f(v.y);
        s0 += v0; s1 += v1; q0 += v0 * v0; q1 += v1 * v1;
    }
    size_t o = ((size_t)seg * NG + g) * HID + c;
    *(float2*)(psum + o) = make_float2(s0, s1);
    *(float2*)(psq + o) = make_float2(q0, q1);
}

// reduce 8 segment partials -> gsum/gsq
__global__ __launch_bounds__(256) void k_gred(const float* __restrict__ psum, const float* __restrict__ psq,
                                              float* __restrict__ gsum, float* __restrict__ gsq) {
    int idx = blockIdx.x * 256 + threadIdx.x;  // NG*HID
    float s = 0.f, q = 0.f;
    #pragma unroll
    for (int seg = 0; seg < 8; ++seg) {
        s += psum[(size_t)seg * NG * HID + idx];
        q += psq[(size_t)seg * NG * HID + idx];
    }
    gsum[idx] = s;
    gsq[idx] = q;
}

// ---------------- GraphNorm apply + ReLU + residual (layers 0..L-2, bf16 stream) ----------------
__global__ __launch_bounds__(256) void k_gapply(const unsigned short* __restrict__ r,
                                                unsigned short* __restrict__ h_bf,
                                                const int* __restrict__ gid,
                                                const float* __restrict__ rcnt,
                                                const float* __restrict__ gsum, const float* __restrict__ gsq,
                                                const float* __restrict__ gw, const float* __restrict__ gb,
                                                const float* __restrict__ gms) {
    int n = blockIdx.x * 2 + (threadIdx.x >> 7);
    int c = (threadIdx.x & 127) * 4;
    int g = gid[n];
    float rc = rcnt[g];
    const float4 sm = *(const float4*)(gsum + (size_t)g * HID + c);
    const float4 sq = *(const float4*)(gsq + (size_t)g * HID + c);
    const float4 ms = *(const float4*)(gms + c);
    const float4 gwv = *(const float4*)(gw + c);
    const float4 gbv = *(const float4*)(gb + c);
    const ushort4 rv4 = *(const ushort4*)(r + (size_t)n * HID + c);
    const ushort4 hv4 = *(const ushort4*)(h_bf + (size_t)n * HID + c);
    float rv[4] = {bf2f(rv4.x), bf2f(rv4.y), bf2f(rv4.z), bf2f(rv4.w)};
    float hv[4] = {bf2f(hv4.x), bf2f(hv4.y), bf2f(hv4.z), bf2f(hv4.w)};
    float outv[4];
    float mean, am, var, wgt, v;
    #define CH(X, K)                                                \
        mean = sm.X * rc; am = ms.X * mean;                         \
        var = sq.X * rc - 2.f * am * mean + am * am;                \
        wgt = gwv.X * rsqrtf(var + 1e-6f);                          \
        v = (rv[K] - am) * wgt + gbv.X;                             \
        v = fmaxf(v, 0.f);                                          \
        outv[K] = v + hv[K];
    CH(x, 0)
    CH(y, 1)
    CH(z, 2)
    CH(w, 3)
    #undef CH
    ushort4 pk;
    pk.x = f2bf(outv[0]); pk.y = f2bf(outv[1]); pk.z = f2bf(outv[2]); pk.w = f2bf(outv[3]);
    *(ushort4*)(h_bf + (size_t)n * HID + c) = pk;
}

// ---------------- Last layer: apply + residual + segmented pool partials (no atomics) ----------------
__global__ __launch_bounds__(256) void k_gpool(const unsigned short* __restrict__ r,
                                               const unsigned short* __restrict__ h_bf,
                                               const int* __restrict__ gs,
                                               const float* __restrict__ rcnt,
                                               const float* __restrict__ gsum, const float* __restrict__ gsq,
                                               const float* __restrict__ gw, const float* __restrict__ gb,
                                               const float* __restrict__ gms,
                                               float* __restrict__ ppool) {
    int g = blockIdx.x;
    int seg = blockIdx.y;
    int s = gs[g], e = gs[g + 1];
    int c = threadIdx.x * 2;
    float rc = rcnt[g];
    // per-channel norm constants (2 channels)
    float2 sm = *(const float2*)(gsum + (size_t)g * HID + c);
    float2 sq = *(const float2*)(gsq + (size_t)g * HID + c);
    float2 ms = *(const float2*)(gms + c);
    float2 gwv = *(const float2*)(gw + c);
    float2 gbv = *(const float2*)(gb + c);
    float mean0 = sm.x * rc, am0 = ms.x * mean0;
    float var0 = sq.x * rc - 2.f * am0 * mean0 + am0 * am0;
    float wgt0 = gwv.x * rsqrtf(var0 + 1e-6f);
    float mean1 = sm.y * rc, am1 = ms.y * mean1;
    float var1 = sq.y * rc - 2.f * am1 * mean1 + am1 * am1;
    float wgt1 = gwv.y * rsqrtf(var1 + 1e-6f);
    float p0 = 0.f, p1 = 0.f;
    for (int n = s + seg; n < e; n += 8) {
        ushort2 rv = *(const ushort2*)(r + (size_t)n * HID + c);
        ushort2 hv = *(const ushort2*)(h_bf + (size_t)n * HID + c);
        p0 += (bf2f(rv.x) - am0) * wgt0 + gbv.x + bf2f(hv.x);
        p1 += (bf2f(rv.y) - am1) * wgt1 + gbv.y + bf2f(hv.y);
    }
    size_t o = ((size_t)seg * NG + g) * HID + c;
    *(float2*)(ppool + o) = make_float2(p0, p1);
}

// ---------------- Final projection (folds 8 pool partials) ----------------
__global__ __launch_bounds__(128) void k_proj(const float* __restrict__ ppool,
                                              const float* __restrict__ Wp,
                                              const float* __restrict__ bp, float* __restrict__ out) {
    int g = blockIdx.x;
    int tid = threadIdx.x;
    __shared__ float pr[HID];
    // fold partials: 128 threads x 4 channels
    {
        int c = tid * 4;
        float4 sv = make_float4(0.f, 0.f, 0.f, 0.f);
        #pragma unroll
        for (int seg = 0; seg < 8; ++seg) {
            const float4 v = *(const float4*)(ppool + ((size_t)seg * NG + g) * HID + c);
            sv.x += v.x; sv.y += v.y; sv.z += v.z; sv.w += v.w;
        }
        *(float4*)(pr + c) = sv;
    }
    __syncthreads();
    int o = tid;
    float acc = bp[o];
    #pragma unroll 8
    for (int k = 0; k < HID; ++k) acc += pr[k] * Wp[k * NOUT + o];
    out[g * NOUT + o] = acc;
}

extern "C" void kernel_launch(void* const* d_in, const int* in_sizes, int n_in,
                              void* d_out, int out_size, void* d_ws, size_t ws_size,
                              hipStream_t stream) {
    const int*   h_node = (const int*)d_in[0];
    const int*   h_edge = (const int*)d_in[1];
    const int*   src    = (const int*)d_in[2];
    const int*   dst    = (const int*)d_in[3];
    const int*   gid    = (const int*)d_in[4];
    const float* aemb   = (const float*)d_in[5];
    const float* bemb   = (const float*)d_in[6];
    const float* W      = (const float*)d_in[7];
    const float* bias   = (const float*)d_in[8];
    const float* gnw    = (const float*)d_in[9];
    const float* gnb    = (const float*)d_in[10];
    const float* gnms   = (const float*)d_in[11];
    const float* Wp     = (const float*)d_in[12];
    const float* bp     = (const float*)d_in[13];
    float* out = (float*)d_out;

    char* ws = (char*)d_ws;
    size_t off = 0;
    auto alloc = [&](size_t bytes) -> char* {
        char* p = ws + off;
        off += (bytes + 255) & ~(size_t)255;
        return p;
    };
    // zero-group first (one contiguous memset): cnt | fc
    int* cnt            = (int*)alloc((size_t)N_NODES * 4);
    int* fc             = (int*)alloc((size_t)N_NODES * 4);
    size_t zbytes = off;

    unsigned short* h_bf= (unsigned short*)alloc((size_t)N_NODES * HID * 2);
    unsigned short* rbf = (unsigned short*)alloc((size_t)N_NODES * HID * 2);
    unsigned short* t   = (unsigned short*)alloc((size_t)N_NODES * HID * 2);
    unsigned short* Wt  = (unsigned short*)alloc((size_t)NL * HID * HID * 2);
    unsigned short* ctab= (unsigned short*)alloc((size_t)NL * 512 * HID * 2);
    int2* ep            = (int2*)alloc((size_t)N_EDGES * 8);
    int* rs             = (int*)alloc((size_t)(N_NODES + 1) * 4);
    int* gs             = (int*)alloc((size_t)(NG + 1) * 4);
    float* rcnt         = (float*)alloc((size_t)NG * 4);
    float* pstat        = (float*)alloc((size_t)2 * 8 * NG * HID * 4);
    float* gstat        = (float*)alloc((size_t)2 * NG * HID * 4);
    float* ppool        = (float*)alloc((size_t)8 * NG * HID * 4);
    float* psum = pstat;
    float* psq  = pstat + (size_t)8 * NG * HID;
    float* gsum = gstat;
    float* gsq  = gstat + (size_t)NG * HID;

    hipMemsetAsync(cnt, 0, zbytes, stream);
    k_prep<<<17409, 256, 0, stream>>>(h_node, aemb, h_bf, dst, cnt, W, Wt, bemb, ctab,
                                      gid, gs, rcnt);
    k_scan<<<1, 256, 0, stream>>>(cnt, rs);
    k_fillep<<<N_EDGES / 256, 256, 0, stream>>>(dst, rs, fc, src, h_edge, ep);

    for (int i = 0; i < NL; ++i) {
        k_neigh<<<N_NODES / 4, 256, 0, stream>>>(h_bf, ep, rs,
                                                 ctab + (size_t)i * 512 * HID, t);
        dim3 gg(N_NODES / BM, HID / BN);
        k_gemm<<<gg, 256, 0, stream>>>(t, Wt + (size_t)i * HID * HID, bias + i * HID, rbf);
        k_gstats<<<dim3(NG, 8), 256, 0, stream>>>(rbf, gs, psum, psq);
        k_gred<<<NG * HID / 256, 256, 0, stream>>>(psum, psq, gsum, gsq);
        if (i < NL - 1) {
            k_gapply<<<N_NODES / 2, 256, 0, stream>>>(rbf, h_bf, gid, rcnt, gsum, gsq,
                                                      gnw + i * HID, gnb + i * HID, gnms + i * HID);
        } else {
            k_gpool<<<dim3(NG, 8), 256, 0, stream>>>(rbf, h_bf, gs, rcnt, gsum, gsq,
                                                     gnw + i * HID, gnb + i * HID, gnms + i * HID,
                                                     ppool);
        }
    }
    k_proj<<<NG, NOUT, 0, stream>>>(ppool, Wp, bp, out);
}